// Round 1
// 1098.100 us; speedup vs baseline: 1.9108x; 1.9108x over previous
//
#include <hip/hip_runtime.h>
#include <stdint.h>

#define B_  2048
#define T_  64
#define D_  512
#define S_  256
#define P_  11
#define H1_ 384
#define NG_ 1152   // H1 + 3S
#define KH_ 256

typedef unsigned short ushort_t;
typedef __attribute__((ext_vector_type(4))) float    f32x4;
typedef __attribute__((ext_vector_type(8))) __bf16   bf16x8;
typedef __attribute__((ext_vector_type(8))) unsigned short u16x8;

static __device__ __forceinline__ ushort_t f2bf(float f) {
    uint32_t u = __builtin_bit_cast(uint32_t, f);
    u += 0x7fffu + ((u >> 16) & 1u);
    return (ushort_t)(u >> 16);
}
static __device__ __forceinline__ float bf2f(ushort_t h) {
    uint32_t u = ((uint32_t)h) << 16;
    return __builtin_bit_cast(float, u);
}
static __device__ __forceinline__ u16x8 ntload8(const ushort_t* p) {
    return __builtin_nontemporal_load((const u16x8*)p);
}

// ---------------------------------------------------------------- pack weights
// WcatA: [1152][512] bf16 row-major (for gemm_pre)
// WhBp : fragment-packed WhB for the recurrent gates GEMM:
//        index = ((nt*8 + kc)*64 + lane)*8 + j
//        holds element (row = nt*16 + (lane&15), col = kc*32 + (lane>>4)*8 + j)
//        of [W1[:,512:768] ; Whh]  (1152 x 256)
__global__ void pack_weights(const float* __restrict__ W1,   // [384][768]
                             const float* __restrict__ Wih,  // [768][513]
                             const float* __restrict__ Whh,  // [768][256]
                             ushort_t* __restrict__ WcatA,
                             ushort_t* __restrict__ WhBp) {
    int idx = blockIdx.x * 256 + threadIdx.x;
    const int tot1 = NG_ * D_;                 // 589824
    if (idx < tot1) {
        int n = idx >> 9;
        int k = idx & 511;
        float v = (n < H1_) ? W1[n * 768 + k] : Wih[(n - H1_) * 513 + k];
        WcatA[idx] = f2bf(v);
    } else {
        int i = idx - tot1;                    // < 294912
        int j  = i & 7;
        int l  = (i >> 3) & 63;
        int kc = (i >> 9) & 7;
        int nt = i >> 12;                      // 0..71
        int row = nt * 16 + (l & 15);
        int col = kc * 32 + (l >> 4) * 8 + j;
        float v = (row < H1_) ? W1[row * 768 + 512 + col] : Whh[(row - H1_) * 256 + col];
        WhBp[i] = f2bf(v);
    }
}

// ---------------------------------------------------------------- phase A GEMM
// pre[t][b][n] = sum_k feat[(b,t)][k] * WcatA[n][k]   (bf16 out, fp32 accum)
__global__ __launch_bounds__(256) void gemm_pre(
        const float* __restrict__ feat,      // [131072][512], row m = b*64+t
        const ushort_t* __restrict__ WcatA,  // [1152][512]
        ushort_t* __restrict__ pre) {        // [64][2048][1152]
    __shared__ __attribute__((aligned(16))) ushort_t Asub[128][72];
    __shared__ __attribute__((aligned(16))) ushort_t Bsub[128][72];

    int bx = blockIdx.x;              // 9216 blocks
    int xcd = bx & 7, slot = bx >> 3;
    int mt = (slot / 9) * 8 + xcd;    // 0..1023
    int ntb = slot % 9;               // 0..8
    int m0 = mt * 128, n0 = ntb * 128;

    int tid = threadIdx.x;
    int lane = tid & 63, wave = tid >> 6;
    int wr = wave >> 1, wc = wave & 1;
    int l15 = lane & 15, q = lane >> 4;

    f32x4 acc[4][4];
    #pragma unroll
    for (int i = 0; i < 4; ++i)
        #pragma unroll
        for (int j = 0; j < 4; ++j)
            acc[i][j] = (f32x4){0.f, 0.f, 0.f, 0.f};

    for (int kt = 0; kt < 8; ++kt) {
        int kbase = kt * 64;
        #pragma unroll
        for (int r = 0; r < 4; ++r) {
            int c = tid + 256 * r;
            int row = c >> 3, sub = c & 7;
            const float* gp = feat + (size_t)(m0 + row) * 512 + kbase + sub * 8;
            f32x4 f0 = *(const f32x4*)gp;
            f32x4 f1 = *(const f32x4*)(gp + 4);
            u16x8 o;
            #pragma unroll
            for (int j = 0; j < 4; ++j) { o[j] = f2bf(f0[j]); o[4 + j] = f2bf(f1[j]); }
            *(u16x8*)&Asub[row][sub * 8] = o;
        }
        #pragma unroll
        for (int r = 0; r < 4; ++r) {
            int c = tid + 256 * r;
            int row = c >> 3, sub = c & 7;
            u16x8 w = *(const u16x8*)(WcatA + (size_t)(n0 + row) * 512 + kbase + sub * 8);
            *(u16x8*)&Bsub[row][sub * 8] = w;
        }
        __syncthreads();
        #pragma unroll
        for (int kc = 0; kc < 2; ++kc) {
            bf16x8 af[4], bfr[4];
            #pragma unroll
            for (int i = 0; i < 4; ++i)
                af[i] = __builtin_bit_cast(bf16x8,
                    *(const u16x8*)&Asub[wr * 64 + i * 16 + l15][kc * 32 + q * 8]);
            #pragma unroll
            for (int j = 0; j < 4; ++j)
                bfr[j] = __builtin_bit_cast(bf16x8,
                    *(const u16x8*)&Bsub[wc * 64 + j * 16 + l15][kc * 32 + q * 8]);
            #pragma unroll
            for (int i = 0; i < 4; ++i)
                #pragma unroll
                for (int j = 0; j < 4; ++j)
                    acc[i][j] = __builtin_amdgcn_mfma_f32_16x16x32_bf16(
                        af[i], bfr[j], acc[i][j], 0, 0, 0);
        }
        __syncthreads();
    }
    #pragma unroll
    for (int i = 0; i < 4; ++i) {
        #pragma unroll
        for (int r = 0; r < 4; ++r) {
            int m = m0 + wr * 64 + i * 16 + q * 4 + r;
            int orow = (m & 63) * 2048 + (m >> 6);   // t*2048 + b
            ushort_t* op = pre + (size_t)orow * NG_ + n0 + wc * 64 + l15;
            #pragma unroll
            for (int j = 0; j < 4; ++j)
                __builtin_nontemporal_store(f2bf(acc[i][j][r]), &op[j * 16]);
        }
    }
}

// ---------------------------------------------------------------- phase B: recurrence
// 256 blocks x 1024 threads; block owns 8 batch rows, loops t=0..63.
// One block per CU (LDS ~90 KB), 16 waves/CU = 4 waves/SIMD.
__global__ __launch_bounds__(1024, 4) void recurrent(
        const float* __restrict__ u,       // [2048][64][11]
        const float* __restrict__ b1,      // [384]
        const float* __restrict__ W2,      // [11][384]
        const float* __restrict__ b2,      // [11]
        const float* __restrict__ temp_p,  // [1]
        const float* __restrict__ Wih,     // [768][513] (col 512 = w_pos)
        const float* __restrict__ bih,     // [768]
        const float* __restrict__ bhh,     // [768]
        const float* __restrict__ h0,      // [256]
        const ushort_t* __restrict__ WhBp, // fragment-packed [72][8][64][8] bf16
        const ushort_t* __restrict__ pre,  // [64][2048][1152] bf16
        float* __restrict__ out_pos,       // [2048][64]
        float* __restrict__ out_states,    // [2048][64][256]
        float* __restrict__ out_hfin) {    // [2048][256]
    // row strides: %32 dwords == 4 (gates/preg/hb/hidb/w2s) — no power-of-2 aliasing
    __shared__ __attribute__((aligned(16))) ushort_t gates[8][1160];
    __shared__ __attribute__((aligned(16))) ushort_t preg[8][1160];
    __shared__ __attribute__((aligned(16))) float    hf[8][256];
    __shared__ __attribute__((aligned(16))) ushort_t hb[16][264];    // rows 8..15 zero
    __shared__ __attribute__((aligned(16))) ushort_t hidb[16][392];  // rows 8..15 zero
    __shared__ __attribute__((aligned(16))) ushort_t w2s[16][392];   // W2 bf16, rows 11..15 zero
    __shared__ __attribute__((aligned(16))) float    b1s[384];
    __shared__ __attribute__((aligned(16))) float    wps[768];
    __shared__ __attribute__((aligned(16))) float    bihs[768];
    __shared__ __attribute__((aligned(16))) float    bhhs[768];
    __shared__ float    b2s[16];
    __shared__ float    logit_s[8][17];
    __shared__ float    pos_s[8];
    __shared__ float    u_s[8][12];

    const int tid  = threadIdx.x;
    const int lane = tid & 63, wave = tid >> 6;       // 16 waves
    const int l15  = lane & 15, q = lane >> 4;
    const int row8 = tid >> 7;                        // elementwise row 0..7
    const int ln128 = tid & 127;                      // elementwise lane 0..127
    const int b0 = blockIdx.x * 8;

    // ---------------- one-time init ----------------
    for (int i = tid; i < 384; i += 1024) b1s[i] = b1[i];
    for (int i = tid; i < 768; i += 1024) {
        wps[i]  = Wih[i * 513 + 512];
        bihs[i] = bih[i];
        bhhs[i] = bhh[i];
    }
    if (tid < 11) b2s[tid] = b2[tid];
    for (int i = tid; i < 16 * 392; i += 1024) {
        int r = i / 392, c = i - r * 392;
        float v = (r < 11 && c < 384) ? W2[r * 384 + c] : 0.f;
        w2s[r][c] = f2bf(v);
    }
    for (int i = tid; i < 8 * 256; i += 1024) {
        int m = i >> 8, s = i & 255;
        float v = h0[s];
        hf[m][s] = v;
        hb[m][s] = f2bf(v);
    }
    for (int i = tid; i < 8 * 264; i += 1024) {      // zero hb rows 8..15
        int m = 8 + i / 264;
        hb[m][i % 264] = 0;
    }
    for (int i = tid; i < 8 * 392; i += 1024) {      // zero hidb rows 8..15
        int m = 8 + i / 392;
        hidb[m][i % 392] = 0;
    }
    float tinv = 1.0f / temp_p[0];

    // ---------------- prologue: stage t=0 pre rows + u ----------------
    u16x8 pr[2];
    {
        const size_t prow = (size_t)b0;              // t=0
        #pragma unroll
        for (int r = 0; r < 2; ++r) {
            int c = tid + (r << 10);
            if (c < 1152) {
                int row = c / 144, off = c - row * 144;
                pr[r] = ntload8(pre + (prow + row) * NG_ + (size_t)off * 8);
            }
        }
    }
    float uval = 0.f;
    const int um = tid / 11, up = tid - um * 11;     // for tid < 88
    if (tid < 88) uval = u[((size_t)(b0 + um) * 64 + 0) * 11 + up];
    __syncthreads();

    for (int t = 0; t < 64; ++t) {
        // commit staged pre/u to LDS (loads issued last iteration — latency hidden)
        #pragma unroll
        for (int r = 0; r < 2; ++r) {
            int c = tid + (r << 10);
            if (c < 1152) {
                int row = c / 144, off = c - row * 144;
                *(u16x8*)&preg[row][off * 8] = pr[r];
            }
        }
        if (tid < 88) u_s[um][up] = uval;

        // A-fragments of h (written by previous step's GRU phase)
        bf16x8 af[8];
        #pragma unroll
        for (int kc = 0; kc < 8; ++kc)
            af[kc] = __builtin_bit_cast(bf16x8, *(const u16x8*)&hb[l15][kc * 32 + q * 8]);

        // -------- phase-1 gates GEMM: cols 0..383 (tiles 0..23 over 16 waves) --------
        for (int nt = wave; nt < 24; nt += 16) {
            f32x4 acc = (f32x4){0.f, 0.f, 0.f, 0.f};
            const ushort_t* wp = WhBp + (((size_t)nt * 8) << 9) + (lane << 3);
            #pragma unroll
            for (int kc = 0; kc < 8; ++kc) {
                bf16x8 bfr = __builtin_bit_cast(bf16x8, *(const u16x8*)(wp + ((size_t)kc << 9)));
                acc = __builtin_amdgcn_mfma_f32_16x16x32_bf16(af[kc], bfr, acc, 0, 0, 0);
            }
            if (q < 2) {
                int n = nt * 16 + l15;
                #pragma unroll
                for (int r = 0; r < 4; ++r)
                    gates[q * 4 + r][n] = f2bf(acc[r]);
            }
        }
        __syncthreads();                                   // B1

        // hidden = relu(gates[:, :384] + pre1 + b1) -> bf16, vectorized 8-wide
        if (ln128 < 48) {
            int c = ln128 << 3;
            u16x8 g8 = *(const u16x8*)&gates[row8][c];
            u16x8 p8 = *(const u16x8*)&preg[row8][c];
            f32x4 ba = *(const f32x4*)&b1s[c];
            f32x4 bb = *(const f32x4*)&b1s[c + 4];
            u16x8 o;
            #pragma unroll
            for (int jj = 0; jj < 8; ++jj) {
                float bv = (jj < 4) ? ba[jj] : bb[jj - 4];
                float v = bf2f(g8[jj]) + bf2f(p8[jj]) + bv;
                o[jj] = f2bf(fmaxf(v, 0.f));
            }
            *(u16x8*)&hidb[row8][c] = o;
        }
        __syncthreads();                                   // B2

        if (wave == 0) {
            // logits MFMA + in-wave softmax (overlaps other waves' phase-2 GEMM)
            f32x4 lacc = (f32x4){0.f, 0.f, 0.f, 0.f};
            #pragma unroll
            for (int kc = 0; kc < 12; ++kc) {
                bf16x8 ha = __builtin_bit_cast(bf16x8,
                    *(const u16x8*)&hidb[l15][kc * 32 + q * 8]);
                bf16x8 wb = __builtin_bit_cast(bf16x8,
                    *(const u16x8*)&w2s[l15][kc * 32 + q * 8]);
                lacc = __builtin_amdgcn_mfma_f32_16x16x32_bf16(ha, wb, lacc, 0, 0, 0);
            }
            if (q < 2) {
                #pragma unroll
                for (int r = 0; r < 4; ++r)
                    logit_s[q * 4 + r][l15] = lacc[r];
            }
            __builtin_amdgcn_s_waitcnt(0);   // drain LDS writes, then in-wave read
            if (lane < 8) {
                int m = lane;
                float lg[11];
                float mx = -1e30f;
                #pragma unroll
                for (int p = 0; p < 11; ++p) {
                    float uu = u_s[m][p];
                    float g = -__logf(-__logf(uu + 1e-20f) + 1e-20f);
                    float a = (logit_s[m][p] + b2s[p] + g) * tinv;
                    lg[p] = a;
                    mx = fmaxf(mx, a);
                }
                float se = 0.f, sp = 0.f;
                #pragma unroll
                for (int p = 0; p < 11; ++p) {
                    float e = __expf(lg[p] - mx);
                    se += e;
                    sp += e * (float)p;
                }
                float pos = sp / se;
                pos_s[m] = pos;
                __builtin_nontemporal_store(pos, &out_pos[(size_t)(b0 + m) * 64 + t]);
            }
        } else {
            // -------- phase-2 gates GEMM: cols 384..1151 (tiles 24..71 over waves 1..15) --------
            for (int nt = 23 + wave; nt < 72; nt += 15) {
                f32x4 acc = (f32x4){0.f, 0.f, 0.f, 0.f};
                const ushort_t* wp = WhBp + (((size_t)nt * 8) << 9) + (lane << 3);
                #pragma unroll
                for (int kc = 0; kc < 8; ++kc) {
                    bf16x8 bfr = __builtin_bit_cast(bf16x8, *(const u16x8*)(wp + ((size_t)kc << 9)));
                    acc = __builtin_amdgcn_mfma_f32_16x16x32_bf16(af[kc], bfr, acc, 0, 0, 0);
                }
                if (q < 2) {
                    int n = nt * 16 + l15;
                    #pragma unroll
                    for (int r = 0; r < 4; ++r)
                        gates[q * 4 + r][n] = f2bf(acc[r]);
                }
            }
        }

        // prefetch next step's pre rows + u (consumed at next iteration's commit;
        // HBM latency covered by B4 + GRU phase + B5)
        if (t < 63) {
            const size_t prow = (size_t)(t + 1) * 2048 + b0;
            #pragma unroll
            for (int r = 0; r < 2; ++r) {
                int c = tid + (r << 10);
                if (c < 1152) {
                    int row = c / 144, off = c - row * 144;
                    pr[r] = ntload8(pre + (prow + row) * NG_ + (size_t)off * 8);
                }
            }
            if (tid < 88) uval = u[((size_t)(b0 + um) * 64 + (t + 1)) * 11 + up];
        }
        __syncthreads();                                   // B4 (pos + phase-2 gates visible)

        // GRU update
        {
            float pos = pos_s[row8];
            float* st = out_states + ((size_t)(b0 + row8) * 64 + t) * 256;
            #pragma unroll
            for (int j = 0; j < 2; ++j) {
                int s = ln128 + (j << 7);
                float ar  = bf2f(preg[row8][384 + s]) + bihs[s]
                          + bf2f(gates[row8][384 + s]) + bhhs[s];
                float az  = bf2f(preg[row8][640 + s]) + bihs[256 + s]
                          + bf2f(gates[row8][640 + s]) + bhhs[256 + s];
                float in0 = bf2f(preg[row8][896 + s]) + bihs[512 + s];
                float gn  = bf2f(gates[row8][896 + s]) + bhhs[512 + s];
                float hp  = hf[row8][s];
                float rr = __builtin_amdgcn_rcpf(1.f + __expf(-(ar + pos * wps[s])));
                float zz = __builtin_amdgcn_rcpf(1.f + __expf(-(az + pos * wps[256 + s])));
                float xn = in0 + pos * wps[512 + s] + rr * gn;
                float e2 = __expf(2.f * xn);
                float nn = 1.f - 2.f * __builtin_amdgcn_rcpf(e2 + 1.f);
                float hnew = (1.f - zz) * nn + zz * hp;
                hf[row8][s] = hnew;
                hb[row8][s] = f2bf(hnew);
                __builtin_nontemporal_store(hnew, st + s);
            }
        }
        __syncthreads();                                   // B5
    }

    for (int i = tid; i < 8 * 256; i += 1024) {
        int m = i >> 8, s = i & 255;
        __builtin_nontemporal_store(hf[m][s], &out_hfin[(size_t)(b0 + m) * 256 + s]);
    }
}

// ---------------------------------------------------------------- launch
extern "C" void kernel_launch(void* const* d_in, const int* in_sizes, int n_in,
                              void* d_out, int out_size, void* d_ws, size_t ws_size,
                              hipStream_t stream) {
    const float* feat = (const float*)d_in[0];
    const float* u    = (const float*)d_in[1];
    const float* W1   = (const float*)d_in[2];
    const float* b1   = (const float*)d_in[3];
    const float* W2   = (const float*)d_in[4];
    const float* b2   = (const float*)d_in[5];
    const float* temp = (const float*)d_in[6];
    const float* Wih  = (const float*)d_in[7];
    const float* bih  = (const float*)d_in[8];
    const float* Whh  = (const float*)d_in[9];
    const float* bhh  = (const float*)d_in[10];
    const float* h0   = (const float*)d_in[11];

    ushort_t* WcatA = (ushort_t*)d_ws;            // [1152][512]
    ushort_t* WhBp  = WcatA + NG_ * D_;           // [72][8][64][8] packed
    ushort_t* pre   = WhBp + NG_ * KH_;           // [64][2048][1152]

    float* out_pos    = (float*)d_out;
    float* out_states = out_pos + (size_t)B_ * T_;
    float* out_hfin   = out_states + (size_t)B_ * T_ * S_;

    pack_weights<<<3456, 256, 0, stream>>>(W1, Wih, Whh, WcatA, WhBp);
    gemm_pre<<<9216, 256, 0, stream>>>(feat, WcatA, pre);
    recurrent<<<256, 1024, 0, stream>>>(u, b1, W2, b2, temp, Wih, bih, bhh, h0,
                                        WhBp, pre, out_pos, out_states, out_hfin);
}